// Round 1
// baseline (295.838 us; speedup 1.0000x reference)
//
#include <hip/hip_runtime.h>
#include <math.h>

#define N_NODES 10000
#define N_EDGES 640000

// ---------------- degree histogram ----------------
__global__ void k_degree(const int* __restrict__ dst, int* __restrict__ counts, int E) {
    int i = blockIdx.x * blockDim.x + threadIdx.x;
    if (i < E) atomicAdd(&counts[dst[i]], 1);
}

// ---------------- exclusive scan over 10000 counts + dis = rsqrt(deg+1) ----------------
__global__ void k_scan(const int* __restrict__ counts, int* __restrict__ offsets,
                       float* __restrict__ dis, int n) {
    __shared__ int sums[1024];
    int tid = threadIdx.x;
    const int per = (n + 1023) / 1024;
    int start = tid * per;
    int end   = min(start + per, n);
    int s = 0;
    for (int i = start; i < end; ++i) s += counts[i];
    sums[tid] = s;
    __syncthreads();
    // Hillis-Steele inclusive scan
    for (int off = 1; off < 1024; off <<= 1) {
        int t = (tid >= off) ? sums[tid - off] : 0;
        __syncthreads();
        sums[tid] += t;
        __syncthreads();
    }
    int run = sums[tid] - s;  // exclusive prefix at chunk start
    for (int i = start; i < end; ++i) {
        offsets[i] = run;
        run += counts[i];
        // self-loop included: deg_total = counts + 1 >= 1, so rsqrt is safe
        dis[i] = rsqrtf((float)(counts[i] + 1));
    }
    if (tid == 1023) offsets[n] = sums[1023];
}

// ---------------- CSR scatter (src ids grouped by dst) ----------------
__global__ void k_scatter(const int* __restrict__ src, const int* __restrict__ dst,
                          const int* __restrict__ offsets, int* __restrict__ cursor,
                          int* __restrict__ csr_src, int E) {
    int i = blockIdx.x * blockDim.x + threadIdx.x;
    if (i < E) {
        int d = dst[i];
        int pos = offsets[d] + atomicAdd(&cursor[d], 1);
        csr_src[pos] = src[i];
    }
}

// ---------------- GEMM: Y[n,128] = X[n,128] @ W[128,128] (+ bias) ----------------
// 256 threads, 32-row tile. Thread t: cols 4*(t&31).., rows (t>>5)*4 + p.
__global__ __launch_bounds__(256) void k_gemm(const float* __restrict__ X,
                                              const float* __restrict__ W,
                                              const float* __restrict__ bias,
                                              float* __restrict__ Y, int n) {
    __shared__ float xs[32 * 128];
    __shared__ float ws[128 * 128];
    int t = threadIdx.x;
    int tile0 = blockIdx.x * 32;

    const float4* Wv = (const float4*)W;
    float4* wsv = (float4*)ws;
#pragma unroll
    for (int q = 0; q < 16; ++q) wsv[t + 256 * q] = Wv[t + 256 * q];

    const float4* Xv = (const float4*)X;
    float4* xsv = (float4*)xs;
#pragma unroll
    for (int q = 0; q < 4; ++q) {
        int idx = t + 256 * q;           // float4 index in tile (32 per row)
        int row = tile0 + (idx >> 5);
        float4 v = make_float4(0.f, 0.f, 0.f, 0.f);
        if (row < n) v = Xv[(size_t)row * 32 + (idx & 31)];
        xsv[idx] = v;
    }
    __syncthreads();

    int c4 = t & 31;
    int rg = t >> 5;
    float4 acc[4];
#pragma unroll
    for (int p = 0; p < 4; ++p) acc[p] = make_float4(0.f, 0.f, 0.f, 0.f);

    const float4* wsr = (const float4*)ws;
    const float4* xsr = (const float4*)xs;
#pragma unroll 4
    for (int kq = 0; kq < 32; ++kq) {
        float4 w0 = wsr[(4 * kq + 0) * 32 + c4];
        float4 w1 = wsr[(4 * kq + 1) * 32 + c4];
        float4 w2 = wsr[(4 * kq + 2) * 32 + c4];
        float4 w3 = wsr[(4 * kq + 3) * 32 + c4];
#pragma unroll
        for (int p = 0; p < 4; ++p) {
            float4 xv = xsr[(rg * 4 + p) * 32 + kq];
            acc[p].x += xv.x * w0.x + xv.y * w1.x + xv.z * w2.x + xv.w * w3.x;
            acc[p].y += xv.x * w0.y + xv.y * w1.y + xv.z * w2.y + xv.w * w3.y;
            acc[p].z += xv.x * w0.z + xv.y * w1.z + xv.z * w2.z + xv.w * w3.z;
            acc[p].w += xv.x * w0.w + xv.y * w1.w + xv.z * w2.w + xv.w * w3.w;
        }
    }
    float4 bv = make_float4(0.f, 0.f, 0.f, 0.f);
    if (bias) bv = ((const float4*)bias)[c4];
#pragma unroll
    for (int p = 0; p < 4; ++p) {
        int row = tile0 + rg * 4 + p;
        if (row < n) {
            float4 o;
            o.x = acc[p].x + bv.x; o.y = acc[p].y + bv.y;
            o.z = acc[p].z + bv.z; o.w = acc[p].w + bv.w;
            ((float4*)Y)[(size_t)row * 32 + c4] = o;
        }
    }
}

// ---------------- GCN aggregation: Y[i] = dis[i]*(sum_e dis[s]*T[s] + dis[i]*T[i]) + b
// MODE 1: relu(...)   MODE 2: ... + resid[i]
template <int MODE>
__global__ __launch_bounds__(256) void k_agg(const float* __restrict__ T,
                                             const float* __restrict__ dis,
                                             const int* __restrict__ offsets,
                                             const int* __restrict__ csr,
                                             const float* __restrict__ bias,
                                             const float* __restrict__ resid,
                                             float* __restrict__ Y, int n) {
    int wid = (blockIdx.x * blockDim.x + threadIdx.x) >> 6;  // one wave per node
    int lane = threadIdx.x & 63;
    if (wid >= n) return;
    int i = wid;
    int e0 = offsets[i], e1 = offsets[i + 1];
    float a0 = 0.f, a1 = 0.f;
    for (int e = e0; e < e1; ++e) {
        int s = csr[e];
        float w = dis[s];
        a0 += w * T[(size_t)s * 128 + lane];
        a1 += w * T[(size_t)s * 128 + 64 + lane];
    }
    float di = dis[i];
    a0 += di * T[(size_t)i * 128 + lane];
    a1 += di * T[(size_t)i * 128 + 64 + lane];
    a0 = di * a0 + bias[lane];
    a1 = di * a1 + bias[64 + lane];
    if (MODE == 1) {
        a0 = fmaxf(a0, 0.f);
        a1 = fmaxf(a1, 0.f);
    } else {
        a0 += resid[(size_t)i * 128 + lane];
        a1 += resid[(size_t)i * 128 + 64 + lane];
    }
    Y[(size_t)i * 128 + lane] = a0;
    Y[(size_t)i * 128 + 64 + lane] = a1;
}

// ---------------- fused heads: log_softmax(h@Wlin+blin), h@Wdeg2+b, h@Wdeg3+b ----------------
__global__ __launch_bounds__(256) void k_heads(const float* __restrict__ h,
                                               const float* __restrict__ Wlin,
                                               const float* __restrict__ blin,
                                               const float* __restrict__ Wd2,
                                               const float* __restrict__ bd2,
                                               const float* __restrict__ Wd3,
                                               const float* __restrict__ bd3,
                                               float* __restrict__ out1,
                                               float* __restrict__ out2,
                                               float* __restrict__ out3, int n) {
    int wid = (blockIdx.x * blockDim.x + threadIdx.x) >> 6;  // one wave per row
    int lane = threadIdx.x & 63;
    if (wid >= n) return;
    int r = wid;
    float h0 = h[(size_t)r * 128 + lane];
    float h1 = h[(size_t)r * 128 + 64 + lane];
    float p2 = h0 * Wd2[lane] + h1 * Wd2[64 + lane];
    float p3 = h0 * Wd3[lane] + h1 * Wd3[64 + lane];
#pragma unroll
    for (int d = 1; d < 64; d <<= 1) {
        p2 += __shfl_xor(p2, d, 64);
        p3 += __shfl_xor(p3, d, 64);
    }
    if (lane == 0) {
        out2[r] = p2 + bd2[0];
        out3[r] = p3 + bd3[0];
    }
    // classifier head: 4 lane-groups of 16, lane -> col c = lane&15, k-range kg*32..
    int c = lane & 15, kg = lane >> 4;
    float z = 0.f;
#pragma unroll 8
    for (int j = 0; j < 32; ++j) {
        int k = kg * 32 + j;
        z += h[(size_t)r * 128 + k] * Wlin[k * 16 + c];
    }
    z += __shfl_xor(z, 16, 64);
    z += __shfl_xor(z, 32, 64);
    z += blin[c];
    float m = z;
#pragma unroll
    for (int d = 1; d < 16; d <<= 1) m = fmaxf(m, __shfl_xor(m, d, 64));
    float ex = expf(z - m);
    float ssum = ex;
#pragma unroll
    for (int d = 1; d < 16; d <<= 1) ssum += __shfl_xor(ssum, d, 64);
    float lsm = z - m - logf(ssum);
    if (lane < 16) out1[(size_t)r * 16 + c] = lsm;
}

extern "C" void kernel_launch(void* const* d_in, const int* in_sizes, int n_in,
                              void* d_out, int out_size, void* d_ws, size_t ws_size,
                              hipStream_t stream) {
    const float* x     = (const float*)d_in[0];
    const int*   ei    = (const int*)d_in[1];
    const float* W1    = (const float*)d_in[2];
    const float* b1    = (const float*)d_in[3];
    const float* W2    = (const float*)d_in[4];
    const float* b2    = (const float*)d_in[5];
    const float* Wlin1 = (const float*)d_in[6];
    const float* blin1 = (const float*)d_in[7];
    const float* Wdeg2 = (const float*)d_in[8];
    const float* bdeg2 = (const float*)d_in[9];
    const float* Wdeg3 = (const float*)d_in[10];
    const float* bdeg3 = (const float*)d_in[11];
    const float* Wdown = (const float*)d_in[12];
    const float* bdown = (const float*)d_in[13];

    const int n = N_NODES, E = N_EDGES;
    const int* src = ei;
    const int* dst = ei + E;

    // workspace layout (all 16B aligned)
    char* ws = (char*)d_ws;
    int*   counts  = (int*)ws;                       // 10000
    int*   cursor  = counts + n;                     // 10000
    int*   offsets = cursor + n;                     // 10001 (pad 10016)
    float* dis     = (float*)(offsets + 10016);      // 10000
    int*   csr     = (int*)(dis + n);                // 640000
    float* bufA    = (float*)(csr + E);              // 10000*128
    float* bufB    = bufA + (size_t)n * 128;         // 10000*128
    float* bufC    = bufB + (size_t)n * 128;         // 10000*128

    hipMemsetAsync(d_ws, 0, 2 * n * sizeof(int), stream);  // counts + cursor

    k_degree<<<(E + 255) / 256, 256, 0, stream>>>(dst, counts, E);
    k_scan<<<1, 1024, 0, stream>>>(counts, offsets, dis, n);
    k_scatter<<<(E + 255) / 256, 256, 0, stream>>>(src, dst, offsets, cursor, csr, E);

    // T1 = x @ W1 (bias later, in agg)
    k_gemm<<<(n + 31) / 32, 256, 0, stream>>>(x, W1, nullptr, bufA, n);
    // orig = x @ Wdown + bdown
    k_gemm<<<(n + 31) / 32, 256, 0, stream>>>(x, Wdown, bdown, bufB, n);
    // h1 = relu(agg(T1) + b1)
    k_agg<1><<<(n + 3) / 4, 256, 0, stream>>>(bufA, dis, offsets, csr, b1, nullptr, bufC, n);
    // T2 = h1 @ W2
    k_gemm<<<(n + 31) / 32, 256, 0, stream>>>(bufC, W2, nullptr, bufA, n);
    // h2 = agg(T2) + b2 + orig
    k_agg<2><<<(n + 3) / 4, 256, 0, stream>>>(bufA, dis, offsets, csr, b2, bufB, bufC, n);

    float* out1 = (float*)d_out;
    float* out2 = out1 + (size_t)n * 16;
    float* out3 = out2 + n;
    k_heads<<<(n + 3) / 4, 256, 0, stream>>>(bufC, Wlin1, blin1, Wdeg2, bdeg2,
                                             Wdeg3, bdeg3, out1, out2, out3, n);
}

// Round 2
// 217.254 us; speedup vs baseline: 1.3617x; 1.3617x over previous
//
#include <hip/hip_runtime.h>
#include <math.h>

#define N_NODES 10000
#define N_EDGES 640000

// ---------------- degree histogram ----------------
__global__ void k_degree(const int* __restrict__ dst, int* __restrict__ counts, int E) {
    int i = blockIdx.x * blockDim.x + threadIdx.x;
    if (i < E) atomicAdd(&counts[dst[i]], 1);
}

// ---------------- exclusive scan over 10000 counts + dis = rsqrt(deg+1) ----------------
__global__ void k_scan(const int* __restrict__ counts, int* __restrict__ offsets,
                       float* __restrict__ dis, int n) {
    __shared__ int sums[1024];
    int tid = threadIdx.x;
    const int per = (n + 1023) / 1024;
    int start = tid * per;
    int end   = min(start + per, n);
    int s = 0;
    for (int i = start; i < end; ++i) s += counts[i];
    sums[tid] = s;
    __syncthreads();
    // Hillis-Steele inclusive scan
    for (int off = 1; off < 1024; off <<= 1) {
        int t = (tid >= off) ? sums[tid - off] : 0;
        __syncthreads();
        sums[tid] += t;
        __syncthreads();
    }
    int run = sums[tid] - s;  // exclusive prefix at chunk start
    for (int i = start; i < end; ++i) {
        offsets[i] = run;
        run += counts[i];
        // self-loop included: deg_total = counts + 1 >= 1, so rsqrt is safe
        dis[i] = rsqrtf((float)(counts[i] + 1));
    }
    if (tid == 1023) offsets[n] = sums[1023];
}

// ---------------- CSR scatter (src ids grouped by dst) ----------------
__global__ void k_scatter(const int* __restrict__ src, const int* __restrict__ dst,
                          const int* __restrict__ offsets, int* __restrict__ cursor,
                          int* __restrict__ csr_src, int E) {
    int i = blockIdx.x * blockDim.x + threadIdx.x;
    if (i < E) {
        int d = dst[i];
        int pos = offsets[d] + atomicAdd(&cursor[d], 1);
        csr_src[pos] = src[i];
    }
}

// ---------------- GEMM: Y[n,128] = X[n,128] @ W[128,128] (+ bias) ----------------
__global__ __launch_bounds__(256) void k_gemm(const float* __restrict__ X,
                                              const float* __restrict__ W,
                                              const float* __restrict__ bias,
                                              float* __restrict__ Y, int n) {
    __shared__ float xs[32 * 128];
    __shared__ float ws[128 * 128];
    int t = threadIdx.x;
    int tile0 = blockIdx.x * 32;

    const float4* Wv = (const float4*)W;
    float4* wsv = (float4*)ws;
#pragma unroll
    for (int q = 0; q < 16; ++q) wsv[t + 256 * q] = Wv[t + 256 * q];

    const float4* Xv = (const float4*)X;
    float4* xsv = (float4*)xs;
#pragma unroll
    for (int q = 0; q < 4; ++q) {
        int idx = t + 256 * q;           // float4 index in tile (32 per row)
        int row = tile0 + (idx >> 5);
        float4 v = make_float4(0.f, 0.f, 0.f, 0.f);
        if (row < n) v = Xv[(size_t)row * 32 + (idx & 31)];
        xsv[idx] = v;
    }
    __syncthreads();

    int c4 = t & 31;
    int rg = t >> 5;
    float4 acc[4];
#pragma unroll
    for (int p = 0; p < 4; ++p) acc[p] = make_float4(0.f, 0.f, 0.f, 0.f);

    const float4* wsr = (const float4*)ws;
    const float4* xsr = (const float4*)xs;
#pragma unroll 4
    for (int kq = 0; kq < 32; ++kq) {
        float4 w0 = wsr[(4 * kq + 0) * 32 + c4];
        float4 w1 = wsr[(4 * kq + 1) * 32 + c4];
        float4 w2 = wsr[(4 * kq + 2) * 32 + c4];
        float4 w3 = wsr[(4 * kq + 3) * 32 + c4];
#pragma unroll
        for (int p = 0; p < 4; ++p) {
            float4 xv = xsr[(rg * 4 + p) * 32 + kq];
            acc[p].x += xv.x * w0.x + xv.y * w1.x + xv.z * w2.x + xv.w * w3.x;
            acc[p].y += xv.x * w0.y + xv.y * w1.y + xv.z * w2.y + xv.w * w3.y;
            acc[p].z += xv.x * w0.z + xv.y * w1.z + xv.z * w2.z + xv.w * w3.z;
            acc[p].w += xv.x * w0.w + xv.y * w1.w + xv.z * w2.w + xv.w * w3.w;
        }
    }
    float4 bv = make_float4(0.f, 0.f, 0.f, 0.f);
    if (bias) bv = ((const float4*)bias)[c4];
#pragma unroll
    for (int p = 0; p < 4; ++p) {
        int row = tile0 + rg * 4 + p;
        if (row < n) {
            float4 o;
            o.x = acc[p].x + bv.x; o.y = acc[p].y + bv.y;
            o.z = acc[p].z + bv.z; o.w = acc[p].w + bv.w;
            ((float4*)Y)[(size_t)row * 32 + c4] = o;
        }
    }
}

// ---------------- GCN aggregation, block-per-node, 8-way edge-parallel ----------------
// Y[i] = dis[i]*(sum_e dis[s]*T[s] + dis[i]*T[i]) + b ; MODE 1: relu, MODE 2: +resid
template <int MODE>
__global__ __launch_bounds__(256) void k_agg(const float* __restrict__ T,
                                             const float* __restrict__ dis,
                                             const int* __restrict__ offsets,
                                             const int* __restrict__ csr,
                                             const float* __restrict__ bias,
                                             const float* __restrict__ resid,
                                             float* __restrict__ Y, int n) {
    __shared__ float4 red[3][32];
    int i = blockIdx.x;
    int t = threadIdx.x;
    int c4 = t & 31;     // float4 column group (32 x 16B = 128 cols)
    int es = t >> 5;     // edge subset 0..7
    int wave = t >> 6;
    int lane = t & 63;

    int e0 = offsets[i], e1 = offsets[i + 1];
    const float4* T4 = (const float4*)T;

    float4 a0 = make_float4(0.f, 0.f, 0.f, 0.f);
    float4 a1 = make_float4(0.f, 0.f, 0.f, 0.f);
    int e = e0 + es;
    // two independent csr->dis->T chains in flight
    for (; e + 8 < e1; e += 16) {
        int s0 = csr[e];
        int s1 = csr[e + 8];
        float w0 = dis[s0];
        float w1 = dis[s1];
        float4 v0 = T4[(size_t)s0 * 32 + c4];
        float4 v1 = T4[(size_t)s1 * 32 + c4];
        a0.x += w0 * v0.x; a0.y += w0 * v0.y; a0.z += w0 * v0.z; a0.w += w0 * v0.w;
        a1.x += w1 * v1.x; a1.y += w1 * v1.y; a1.z += w1 * v1.z; a1.w += w1 * v1.w;
    }
    if (e < e1) {
        int s0 = csr[e];
        float w0 = dis[s0];
        float4 v0 = T4[(size_t)s0 * 32 + c4];
        a0.x += w0 * v0.x; a0.y += w0 * v0.y; a0.z += w0 * v0.z; a0.w += w0 * v0.w;
    }
    a0.x += a1.x; a0.y += a1.y; a0.z += a1.z; a0.w += a1.w;

    // combine the two edge-subsets within this wave (lanes 0-31 <-> 32-63)
    a0.x += __shfl_xor(a0.x, 32, 64);
    a0.y += __shfl_xor(a0.y, 32, 64);
    a0.z += __shfl_xor(a0.z, 32, 64);
    a0.w += __shfl_xor(a0.w, 32, 64);

    if (wave > 0 && lane < 32) red[wave - 1][c4] = a0;
    __syncthreads();
    if (wave == 0 && lane < 32) {
        float4 r0 = red[0][c4], r1 = red[1][c4], r2 = red[2][c4];
        a0.x += r0.x + r1.x + r2.x;
        a0.y += r0.y + r1.y + r2.y;
        a0.z += r0.z + r1.z + r2.z;
        a0.w += r0.w + r1.w + r2.w;

        float di = dis[i];
        float4 self = T4[(size_t)i * 32 + c4];
        a0.x += di * self.x; a0.y += di * self.y; a0.z += di * self.z; a0.w += di * self.w;

        float4 bv = ((const float4*)bias)[c4];
        a0.x = di * a0.x + bv.x;
        a0.y = di * a0.y + bv.y;
        a0.z = di * a0.z + bv.z;
        a0.w = di * a0.w + bv.w;

        if (MODE == 1) {
            a0.x = fmaxf(a0.x, 0.f); a0.y = fmaxf(a0.y, 0.f);
            a0.z = fmaxf(a0.z, 0.f); a0.w = fmaxf(a0.w, 0.f);
        } else {
            float4 rv = ((const float4*)resid)[(size_t)i * 32 + c4];
            a0.x += rv.x; a0.y += rv.y; a0.z += rv.z; a0.w += rv.w;
        }
        ((float4*)Y)[(size_t)i * 32 + c4] = a0;
    }
}

// ---------------- fused heads ----------------
__global__ __launch_bounds__(256) void k_heads(const float* __restrict__ h,
                                               const float* __restrict__ Wlin,
                                               const float* __restrict__ blin,
                                               const float* __restrict__ Wd2,
                                               const float* __restrict__ bd2,
                                               const float* __restrict__ Wd3,
                                               const float* __restrict__ bd3,
                                               float* __restrict__ out1,
                                               float* __restrict__ out2,
                                               float* __restrict__ out3, int n) {
    int wid = (blockIdx.x * blockDim.x + threadIdx.x) >> 6;  // one wave per row
    int lane = threadIdx.x & 63;
    if (wid >= n) return;
    int r = wid;
    float h0 = h[(size_t)r * 128 + lane];
    float h1 = h[(size_t)r * 128 + 64 + lane];
    float p2 = h0 * Wd2[lane] + h1 * Wd2[64 + lane];
    float p3 = h0 * Wd3[lane] + h1 * Wd3[64 + lane];
#pragma unroll
    for (int d = 1; d < 64; d <<= 1) {
        p2 += __shfl_xor(p2, d, 64);
        p3 += __shfl_xor(p3, d, 64);
    }
    if (lane == 0) {
        out2[r] = p2 + bd2[0];
        out3[r] = p3 + bd3[0];
    }
    int c = lane & 15, kg = lane >> 4;
    float z = 0.f;
#pragma unroll 8
    for (int j = 0; j < 32; ++j) {
        int k = kg * 32 + j;
        z += h[(size_t)r * 128 + k] * Wlin[k * 16 + c];
    }
    z += __shfl_xor(z, 16, 64);
    z += __shfl_xor(z, 32, 64);
    z += blin[c];
    float m = z;
#pragma unroll
    for (int d = 1; d < 16; d <<= 1) m = fmaxf(m, __shfl_xor(m, d, 64));
    float ex = expf(z - m);
    float ssum = ex;
#pragma unroll
    for (int d = 1; d < 16; d <<= 1) ssum += __shfl_xor(ssum, d, 64);
    float lsm = z - m - logf(ssum);
    if (lane < 16) out1[(size_t)r * 16 + c] = lsm;
}

extern "C" void kernel_launch(void* const* d_in, const int* in_sizes, int n_in,
                              void* d_out, int out_size, void* d_ws, size_t ws_size,
                              hipStream_t stream) {
    const float* x     = (const float*)d_in[0];
    const int*   ei    = (const int*)d_in[1];
    const float* W1    = (const float*)d_in[2];
    const float* b1    = (const float*)d_in[3];
    const float* W2    = (const float*)d_in[4];
    const float* b2    = (const float*)d_in[5];
    const float* Wlin1 = (const float*)d_in[6];
    const float* blin1 = (const float*)d_in[7];
    const float* Wdeg2 = (const float*)d_in[8];
    const float* bdeg2 = (const float*)d_in[9];
    const float* Wdeg3 = (const float*)d_in[10];
    const float* bdeg3 = (const float*)d_in[11];
    const float* Wdown = (const float*)d_in[12];
    const float* bdown = (const float*)d_in[13];

    const int n = N_NODES, E = N_EDGES;
    const int* src = ei;
    const int* dst = ei + E;

    char* ws = (char*)d_ws;
    int*   counts  = (int*)ws;                       // 10000
    int*   cursor  = counts + n;                     // 10000
    int*   offsets = cursor + n;                     // 10001 (pad 10016)
    float* dis     = (float*)(offsets + 10016);      // 10000
    int*   csr     = (int*)(dis + n);                // 640000
    float* bufA    = (float*)(csr + E);              // 10000*128
    float* bufB    = bufA + (size_t)n * 128;         // 10000*128
    float* bufC    = bufB + (size_t)n * 128;         // 10000*128

    hipMemsetAsync(d_ws, 0, 2 * n * sizeof(int), stream);  // counts + cursor

    k_degree<<<(E + 255) / 256, 256, 0, stream>>>(dst, counts, E);
    k_scan<<<1, 1024, 0, stream>>>(counts, offsets, dis, n);
    k_scatter<<<(E + 255) / 256, 256, 0, stream>>>(src, dst, offsets, cursor, csr, E);

    // T1 = x @ W1 (bias folded into agg)
    k_gemm<<<(n + 31) / 32, 256, 0, stream>>>(x, W1, nullptr, bufA, n);
    // orig = x @ Wdown + bdown
    k_gemm<<<(n + 31) / 32, 256, 0, stream>>>(x, Wdown, bdown, bufB, n);
    // h1 = relu(agg(T1) + b1)
    k_agg<1><<<n, 256, 0, stream>>>(bufA, dis, offsets, csr, b1, nullptr, bufC, n);
    // T2 = h1 @ W2
    k_gemm<<<(n + 31) / 32, 256, 0, stream>>>(bufC, W2, nullptr, bufA, n);
    // h2 = agg(T2) + b2 + orig
    k_agg<2><<<n, 256, 0, stream>>>(bufA, dis, offsets, csr, b2, bufB, bufC, n);

    float* out1 = (float*)d_out;
    float* out2 = out1 + (size_t)n * 16;
    float* out3 = out2 + n;
    k_heads<<<(n + 3) / 4, 256, 0, stream>>>(bufC, Wlin1, blin1, Wdeg2, bdeg2,
                                             Wdeg3, bdeg3, out1, out2, out3, n);
}

// Round 3
// 190.917 us; speedup vs baseline: 1.5496x; 1.1380x over previous
//
#include <hip/hip_runtime.h>
#include <math.h>

#define N_NODES 10000
#define N_EDGES 640000

typedef unsigned short ushort4_t __attribute__((ext_vector_type(4)));
typedef unsigned short ushort8_t __attribute__((ext_vector_type(8)));

__device__ inline unsigned short f2bf(float f) {
    unsigned int u = __float_as_uint(f);
    u = (u + 0x7FFFu + ((u >> 16) & 1u)) >> 16;   // RNE
    return (unsigned short)u;
}
__device__ inline float bf2f(unsigned short s) {
    return __uint_as_float(((unsigned int)s) << 16);
}

// ---------------- degree histogram, 4 edges/thread ----------------
__global__ void k_degree(const int4* __restrict__ dst4, int* __restrict__ counts, int n4) {
    int i = blockIdx.x * blockDim.x + threadIdx.x;
    if (i < n4) {
        int4 d = dst4[i];
        atomicAdd(&counts[d.x], 1);
        atomicAdd(&counts[d.y], 1);
        atomicAdd(&counts[d.z], 1);
        atomicAdd(&counts[d.w], 1);
    }
}

// ---------------- scan: offsets + cursor init + dis ----------------
__global__ void k_scan(const int* __restrict__ counts, int* __restrict__ offsets,
                       int* __restrict__ cursor, float* __restrict__ dis, int n) {
    __shared__ int sums[1024];
    int tid = threadIdx.x;
    const int per = (n + 1023) / 1024;
    int start = tid * per;
    int end   = min(start + per, n);
    int s = 0;
    for (int i = start; i < end; ++i) s += counts[i];
    sums[tid] = s;
    __syncthreads();
    for (int off = 1; off < 1024; off <<= 1) {
        int t = (tid >= off) ? sums[tid - off] : 0;
        __syncthreads();
        sums[tid] += t;
        __syncthreads();
    }
    int run = sums[tid] - s;
    for (int i = start; i < end; ++i) {
        offsets[i] = run;
        cursor[i]  = run;          // scatter bumps this directly
        run += counts[i];
        dis[i] = rsqrtf((float)(counts[i] + 1));  // +1 self-loop
    }
    if (tid == 1023) offsets[n] = sums[1023];
}

// ---------------- CSR scatter, 4 edges/thread, cursor holds position ----------------
__global__ void k_scatter(const int4* __restrict__ src4, const int4* __restrict__ dst4,
                          int* __restrict__ cursor, int* __restrict__ csr, int n4) {
    int i = blockIdx.x * blockDim.x + threadIdx.x;
    if (i < n4) {
        int4 s = src4[i];
        int4 d = dst4[i];
        int p0 = atomicAdd(&cursor[d.x], 1);
        int p1 = atomicAdd(&cursor[d.y], 1);
        int p2 = atomicAdd(&cursor[d.z], 1);
        int p3 = atomicAdd(&cursor[d.w], 1);
        csr[p0] = s.x;
        csr[p1] = s.y;
        csr[p2] = s.z;
        csr[p3] = s.w;
    }
}

// ---------------- GEMM: Y[n,128] = X[n,128] @ W[128,128] (+bias); f32 or bf16 out ----------------
template <int BF16OUT>
__global__ __launch_bounds__(256) void k_gemm(const float* __restrict__ X,
                                              const float* __restrict__ W,
                                              const float* __restrict__ bias,
                                              void* __restrict__ Yv, int n) {
    __shared__ float xs[32 * 128];
    __shared__ float ws[128 * 128];
    int t = threadIdx.x;
    int tile0 = blockIdx.x * 32;

    const float4* Wv = (const float4*)W;
    float4* wsv = (float4*)ws;
#pragma unroll
    for (int q = 0; q < 16; ++q) wsv[t + 256 * q] = Wv[t + 256 * q];

    const float4* Xv = (const float4*)X;
    float4* xsv = (float4*)xs;
#pragma unroll
    for (int q = 0; q < 4; ++q) {
        int idx = t + 256 * q;
        int row = tile0 + (idx >> 5);
        float4 v = make_float4(0.f, 0.f, 0.f, 0.f);
        if (row < n) v = Xv[(size_t)row * 32 + (idx & 31)];
        xsv[idx] = v;
    }
    __syncthreads();

    int c4 = t & 31;
    int rg = t >> 5;
    float4 acc[4];
#pragma unroll
    for (int p = 0; p < 4; ++p) acc[p] = make_float4(0.f, 0.f, 0.f, 0.f);

    const float4* wsr = (const float4*)ws;
    const float4* xsr = (const float4*)xs;
#pragma unroll 4
    for (int kq = 0; kq < 32; ++kq) {
        float4 w0 = wsr[(4 * kq + 0) * 32 + c4];
        float4 w1 = wsr[(4 * kq + 1) * 32 + c4];
        float4 w2 = wsr[(4 * kq + 2) * 32 + c4];
        float4 w3 = wsr[(4 * kq + 3) * 32 + c4];
#pragma unroll
        for (int p = 0; p < 4; ++p) {
            float4 xv = xsr[(rg * 4 + p) * 32 + kq];
            acc[p].x += xv.x * w0.x + xv.y * w1.x + xv.z * w2.x + xv.w * w3.x;
            acc[p].y += xv.x * w0.y + xv.y * w1.y + xv.z * w2.y + xv.w * w3.y;
            acc[p].z += xv.x * w0.z + xv.y * w1.z + xv.z * w2.z + xv.w * w3.z;
            acc[p].w += xv.x * w0.w + xv.y * w1.w + xv.z * w2.w + xv.w * w3.w;
        }
    }
    float4 bv = make_float4(0.f, 0.f, 0.f, 0.f);
    if (bias) bv = ((const float4*)bias)[c4];
#pragma unroll
    for (int p = 0; p < 4; ++p) {
        int row = tile0 + rg * 4 + p;
        if (row < n) {
            float ox = acc[p].x + bv.x, oy = acc[p].y + bv.y;
            float oz = acc[p].z + bv.z, ow = acc[p].w + bv.w;
            if (BF16OUT) {
                ushort4_t o;
                o[0] = f2bf(ox); o[1] = f2bf(oy); o[2] = f2bf(oz); o[3] = f2bf(ow);
                ((ushort4_t*)Yv)[(size_t)row * 32 + c4] = o;
            } else {
                ((float4*)Yv)[(size_t)row * 32 + c4] = make_float4(ox, oy, oz, ow);
            }
        }
    }
}

// ---------------- GCN aggregation over bf16 T, block/node, 16-way edge-parallel ----------------
// Y[i] = dis[i]*(sum dis[s]*T[s] + dis[i]*T[i]) + b ; MODE 1: relu, MODE 2: +resid
template <int MODE>
__global__ __launch_bounds__(256) void k_agg(const unsigned short* __restrict__ T,
                                             const float* __restrict__ dis,
                                             const int* __restrict__ offsets,
                                             const int* __restrict__ csr,
                                             const float* __restrict__ bias,
                                             const float* __restrict__ resid,
                                             float* __restrict__ Y, int n) {
    __shared__ float red[3][16][9];   // +1 pad: conflict-free
    int i = blockIdx.x;
    int t = threadIdx.x;
    int c8 = t & 15;    // 16 x 16B chunks cover a 256B bf16 row
    int es = t >> 4;    // edge subset 0..15
    int wave = t >> 6;
    int lane = t & 63;

    int e0 = offsets[i], e1 = offsets[i + 1];
    const ushort8_t* T8 = (const ushort8_t*)T;

    float acc[8];
#pragma unroll
    for (int j = 0; j < 8; ++j) acc[j] = 0.f;

    int e = e0 + es;
    for (; e + 16 < e1; e += 32) {   // two independent gather chains
        int s0 = csr[e];
        int s1 = csr[e + 16];
        float w0 = dis[s0];
        float w1 = dis[s1];
        ushort8_t v0 = T8[(size_t)s0 * 16 + c8];
        ushort8_t v1 = T8[(size_t)s1 * 16 + c8];
#pragma unroll
        for (int j = 0; j < 8; ++j)
            acc[j] += w0 * bf2f(v0[j]) + w1 * bf2f(v1[j]);
    }
    if (e < e1) {
        int s0 = csr[e];
        float w0 = dis[s0];
        ushort8_t v0 = T8[(size_t)s0 * 16 + c8];
#pragma unroll
        for (int j = 0; j < 8; ++j) acc[j] += w0 * bf2f(v0[j]);
    }

    // reduce the wave's 4 edge-subsets (lane bits 4,5), c8 stays aligned
#pragma unroll
    for (int j = 0; j < 8; ++j) {
        acc[j] += __shfl_xor(acc[j], 16, 64);
        acc[j] += __shfl_xor(acc[j], 32, 64);
    }
    if (wave > 0 && lane < 16) {
#pragma unroll
        for (int j = 0; j < 8; ++j) red[wave - 1][lane][j] = acc[j];
    }
    __syncthreads();
    if (wave == 0 && lane < 16) {
#pragma unroll
        for (int j = 0; j < 8; ++j)
            acc[j] += red[0][lane][j] + red[1][lane][j] + red[2][lane][j];

        float di = dis[i];
        ushort8_t sv = T8[(size_t)i * 16 + c8];
#pragma unroll
        for (int j = 0; j < 8; ++j) acc[j] += di * bf2f(sv[j]);

#pragma unroll
        for (int j = 0; j < 8; ++j) acc[j] = di * acc[j] + bias[c8 * 8 + j];

        if (MODE == 1) {
#pragma unroll
            for (int j = 0; j < 8; ++j) acc[j] = fmaxf(acc[j], 0.f);
        } else {
            const float4* rv4 = (const float4*)resid;
            float4 r0 = rv4[(size_t)i * 32 + c8 * 2];
            float4 r1 = rv4[(size_t)i * 32 + c8 * 2 + 1];
            acc[0] += r0.x; acc[1] += r0.y; acc[2] += r0.z; acc[3] += r0.w;
            acc[4] += r1.x; acc[5] += r1.y; acc[6] += r1.z; acc[7] += r1.w;
        }
        float4* Y4 = (float4*)Y;
        Y4[(size_t)i * 32 + c8 * 2]     = make_float4(acc[0], acc[1], acc[2], acc[3]);
        Y4[(size_t)i * 32 + c8 * 2 + 1] = make_float4(acc[4], acc[5], acc[6], acc[7]);
    }
}

// ---------------- fused heads ----------------
__global__ __launch_bounds__(256) void k_heads(const float* __restrict__ h,
                                               const float* __restrict__ Wlin,
                                               const float* __restrict__ blin,
                                               const float* __restrict__ Wd2,
                                               const float* __restrict__ bd2,
                                               const float* __restrict__ Wd3,
                                               const float* __restrict__ bd3,
                                               float* __restrict__ out1,
                                               float* __restrict__ out2,
                                               float* __restrict__ out3, int n) {
    int wid = (blockIdx.x * blockDim.x + threadIdx.x) >> 6;
    int lane = threadIdx.x & 63;
    if (wid >= n) return;
    int r = wid;
    float h0 = h[(size_t)r * 128 + lane];
    float h1 = h[(size_t)r * 128 + 64 + lane];
    float p2 = h0 * Wd2[lane] + h1 * Wd2[64 + lane];
    float p3 = h0 * Wd3[lane] + h1 * Wd3[64 + lane];
#pragma unroll
    for (int d = 1; d < 64; d <<= 1) {
        p2 += __shfl_xor(p2, d, 64);
        p3 += __shfl_xor(p3, d, 64);
    }
    if (lane == 0) {
        out2[r] = p2 + bd2[0];
        out3[r] = p3 + bd3[0];
    }
    int c = lane & 15, kg = lane >> 4;
    float z = 0.f;
#pragma unroll 8
    for (int j = 0; j < 32; ++j) {
        int k = kg * 32 + j;
        z += h[(size_t)r * 128 + k] * Wlin[k * 16 + c];
    }
    z += __shfl_xor(z, 16, 64);
    z += __shfl_xor(z, 32, 64);
    z += blin[c];
    float m = z;
#pragma unroll
    for (int d = 1; d < 16; d <<= 1) m = fmaxf(m, __shfl_xor(m, d, 64));
    float ex = expf(z - m);
    float ssum = ex;
#pragma unroll
    for (int d = 1; d < 16; d <<= 1) ssum += __shfl_xor(ssum, d, 64);
    float lsm = z - m - logf(ssum);
    if (lane < 16) out1[(size_t)r * 16 + c] = lsm;
}

extern "C" void kernel_launch(void* const* d_in, const int* in_sizes, int n_in,
                              void* d_out, int out_size, void* d_ws, size_t ws_size,
                              hipStream_t stream) {
    const float* x     = (const float*)d_in[0];
    const int*   ei    = (const int*)d_in[1];
    const float* W1    = (const float*)d_in[2];
    const float* b1    = (const float*)d_in[3];
    const float* W2    = (const float*)d_in[4];
    const float* b2    = (const float*)d_in[5];
    const float* Wlin1 = (const float*)d_in[6];
    const float* blin1 = (const float*)d_in[7];
    const float* Wdeg2 = (const float*)d_in[8];
    const float* bdeg2 = (const float*)d_in[9];
    const float* Wdeg3 = (const float*)d_in[10];
    const float* bdeg3 = (const float*)d_in[11];
    const float* Wdown = (const float*)d_in[12];
    const float* bdown = (const float*)d_in[13];

    const int n = N_NODES, E = N_EDGES;
    const int* src = ei;
    const int* dst = ei + E;

    char* ws = (char*)d_ws;
    int*            counts  = (int*)ws;                        // 10000
    int*            cursor  = counts + n;                      // 10000
    int*            offsets = cursor + n;                      // 10016 pad
    float*          dis     = (float*)(offsets + 10016);       // 10000
    int*            csr     = (int*)(dis + n);                 // 640000
    unsigned short* bufT    = (unsigned short*)(csr + E);      // bf16 10000*128
    float*          bufB    = (float*)(bufT + (size_t)n * 128);// f32 10000*128
    float*          bufC    = bufB + (size_t)n * 128;          // f32 10000*128

    hipMemsetAsync(counts, 0, n * sizeof(int), stream);

    const int n4 = E / 4;
    k_degree<<<(n4 + 255) / 256, 256, 0, stream>>>((const int4*)dst, counts, n4);
    k_scan<<<1, 1024, 0, stream>>>(counts, offsets, cursor, dis, n);
    k_scatter<<<(n4 + 255) / 256, 256, 0, stream>>>((const int4*)src, (const int4*)dst,
                                                    cursor, csr, n4);

    // T1 = x @ W1  (bf16 out; bias folded into agg)
    k_gemm<1><<<(n + 31) / 32, 256, 0, stream>>>(x, W1, nullptr, bufT, n);
    // orig = x @ Wdown + bdown  (f32)
    k_gemm<0><<<(n + 31) / 32, 256, 0, stream>>>(x, Wdown, bdown, bufB, n);
    // h1 = relu(agg(T1) + b1)  (f32)
    k_agg<1><<<n, 256, 0, stream>>>(bufT, dis, offsets, csr, b1, nullptr, bufC, n);
    // T2 = h1 @ W2  (bf16 out)
    k_gemm<1><<<(n + 31) / 32, 256, 0, stream>>>(bufC, W2, nullptr, bufT, n);
    // h2 = agg(T2) + b2 + orig
    k_agg<2><<<n, 256, 0, stream>>>(bufT, dis, offsets, csr, b2, bufB, bufC, n);

    float* out1 = (float*)d_out;
    float* out2 = out1 + (size_t)n * 16;
    float* out3 = out2 + n;
    k_heads<<<(n + 3) / 4, 256, 0, stream>>>(bufC, Wlin1, blin1, Wdeg2, bdeg2,
                                             Wdeg3, bdeg3, out1, out2, out3, n);
}

// Round 4
// 129.231 us; speedup vs baseline: 2.2892x; 1.4773x over previous
//
#include <hip/hip_runtime.h>
#include <math.h>

#define N_NODES 10000
#define N_EDGES 640000
#define NB      100          // scatter blocks
#define CH      (N_EDGES / NB)  // 6400 edges per block
#define HP      10016        // histogram pitch (padded)

typedef unsigned short ushort4_t __attribute__((ext_vector_type(4)));
typedef unsigned short ushort8_t __attribute__((ext_vector_type(8)));

__device__ inline unsigned short f2bf(float f) {
    unsigned int u = __float_as_uint(f);
    u = (u + 0x7FFFu + ((u >> 16) & 1u)) >> 16;   // RNE
    return (unsigned short)u;
}
__device__ inline float bf2f(unsigned short s) {
    return __uint_as_float(((unsigned int)s) << 16);
}

// ---- pass A: per-block private LDS histogram (no global atomics) ----
__global__ __launch_bounds__(256) void k_hist(const int* __restrict__ dst,
                                              int* __restrict__ h) {
    __shared__ int hs[HP];
    int t = threadIdx.x;
    for (int j = t; j < HP; j += 256) hs[j] = 0;
    __syncthreads();
    int base = blockIdx.x * CH;
#pragma unroll 4
    for (int j = t; j < CH; j += 256) atomicAdd(&hs[dst[base + j]], 1);
    __syncthreads();
    int* out = h + blockIdx.x * HP;
    for (int j = t; j < N_NODES; j += 256) out[j] = hs[j];
}

// ---- pass B1: column sum over NB block-histograms -> deg, dis ----
__global__ __launch_bounds__(256) void k_colsum(const int* __restrict__ h,
                                                int* __restrict__ deg,
                                                float* __restrict__ dis) {
    int i = blockIdx.x * blockDim.x + threadIdx.x;
    if (i >= N_NODES) return;
    int s = 0;
#pragma unroll 10
    for (int b = 0; b < NB; ++b) s += h[b * HP + i];
    deg[i] = s;
    dis[i] = rsqrtf((float)(s + 1));   // +1 self-loop
}

// ---- pass B2: 1-block exclusive scan of deg -> offsets ----
__global__ void k_scan(const int* __restrict__ deg, int* __restrict__ offsets, int n) {
    __shared__ int sums[1024];
    int tid = threadIdx.x;
    const int per = (n + 1023) / 1024;
    int start = tid * per;
    int end   = min(start + per, n);
    int s = 0;
    for (int i = start; i < end; ++i) s += deg[i];
    sums[tid] = s;
    __syncthreads();
    for (int off = 1; off < 1024; off <<= 1) {
        int t = (tid >= off) ? sums[tid - off] : 0;
        __syncthreads();
        sums[tid] += t;
        __syncthreads();
    }
    int run = sums[tid] - s;
    for (int i = start; i < end; ++i) {
        offsets[i] = run;
        run += deg[i];
    }
    if (tid == 1023) offsets[n] = sums[1023];
}

// ---- pass B3: per-(block,node) scatter base ----
__global__ __launch_bounds__(256) void k_base(const int* __restrict__ h,
                                              const int* __restrict__ offsets,
                                              int* __restrict__ base) {
    int i = blockIdx.x * blockDim.x + threadIdx.x;
    if (i >= N_NODES) return;
    int run = offsets[i];
#pragma unroll 10
    for (int b = 0; b < NB; ++b) {
        base[b * HP + i] = run;
        run += h[b * HP + i];
    }
}

// ---- pass C: scatter via private LDS cursors (no global atomics) ----
__global__ __launch_bounds__(256) void k_scatter(const int* __restrict__ src,
                                                 const int* __restrict__ dst,
                                                 const int* __restrict__ base,
                                                 int* __restrict__ csr) {
    __shared__ int cur[N_NODES];
    int t = threadIdx.x;
    const int* mybase = base + blockIdx.x * HP;
    for (int j = t; j < N_NODES; j += 256) cur[j] = mybase[j];
    __syncthreads();
    int off = blockIdx.x * CH;
#pragma unroll 4
    for (int j = t; j < CH; j += 256) {
        int d = dst[off + j];
        int s = src[off + j];
        int p = atomicAdd(&cur[d], 1);
        csr[p] = s;
    }
}

// ---------------- GEMM: Y[n,128] = X[n,128] @ W[128,128] (+bias); f32 or bf16 out ----------------
template <int BF16OUT>
__global__ __launch_bounds__(256) void k_gemm(const float* __restrict__ X,
                                              const float* __restrict__ W,
                                              const float* __restrict__ bias,
                                              void* __restrict__ Yv, int n) {
    __shared__ float xs[32 * 128];
    __shared__ float ws[128 * 128];
    int t = threadIdx.x;
    int tile0 = blockIdx.x * 32;

    const float4* Wv = (const float4*)W;
    float4* wsv = (float4*)ws;
#pragma unroll
    for (int q = 0; q < 16; ++q) wsv[t + 256 * q] = Wv[t + 256 * q];

    const float4* Xv = (const float4*)X;
    float4* xsv = (float4*)xs;
#pragma unroll
    for (int q = 0; q < 4; ++q) {
        int idx = t + 256 * q;
        int row = tile0 + (idx >> 5);
        float4 v = make_float4(0.f, 0.f, 0.f, 0.f);
        if (row < n) v = Xv[(size_t)row * 32 + (idx & 31)];
        xsv[idx] = v;
    }
    __syncthreads();

    int c4 = t & 31;
    int rg = t >> 5;
    float4 acc[4];
#pragma unroll
    for (int p = 0; p < 4; ++p) acc[p] = make_float4(0.f, 0.f, 0.f, 0.f);

    const float4* wsr = (const float4*)ws;
    const float4* xsr = (const float4*)xs;
#pragma unroll 4
    for (int kq = 0; kq < 32; ++kq) {
        float4 w0 = wsr[(4 * kq + 0) * 32 + c4];
        float4 w1 = wsr[(4 * kq + 1) * 32 + c4];
        float4 w2 = wsr[(4 * kq + 2) * 32 + c4];
        float4 w3 = wsr[(4 * kq + 3) * 32 + c4];
#pragma unroll
        for (int p = 0; p < 4; ++p) {
            float4 xv = xsr[(rg * 4 + p) * 32 + kq];
            acc[p].x += xv.x * w0.x + xv.y * w1.x + xv.z * w2.x + xv.w * w3.x;
            acc[p].y += xv.x * w0.y + xv.y * w1.y + xv.z * w2.y + xv.w * w3.y;
            acc[p].z += xv.x * w0.z + xv.y * w1.z + xv.z * w2.z + xv.w * w3.z;
            acc[p].w += xv.x * w0.w + xv.y * w1.w + xv.z * w2.w + xv.w * w3.w;
        }
    }
    float4 bv = make_float4(0.f, 0.f, 0.f, 0.f);
    if (bias) bv = ((const float4*)bias)[c4];
#pragma unroll
    for (int p = 0; p < 4; ++p) {
        int row = tile0 + rg * 4 + p;
        if (row < n) {
            float ox = acc[p].x + bv.x, oy = acc[p].y + bv.y;
            float oz = acc[p].z + bv.z, ow = acc[p].w + bv.w;
            if (BF16OUT) {
                ushort4_t o;
                o[0] = f2bf(ox); o[1] = f2bf(oy); o[2] = f2bf(oz); o[3] = f2bf(ow);
                ((ushort4_t*)Yv)[(size_t)row * 32 + c4] = o;
            } else {
                ((float4*)Yv)[(size_t)row * 32 + c4] = make_float4(ox, oy, oz, ow);
            }
        }
    }
}

// ---------------- GCN aggregation over bf16 T, block/node, 16-way edge-parallel ----------------
template <int MODE>
__global__ __launch_bounds__(256) void k_agg(const unsigned short* __restrict__ T,
                                             const float* __restrict__ dis,
                                             const int* __restrict__ offsets,
                                             const int* __restrict__ csr,
                                             const float* __restrict__ bias,
                                             const float* __restrict__ resid,
                                             float* __restrict__ Y, int n) {
    __shared__ float red[3][16][9];
    int i = blockIdx.x;
    int t = threadIdx.x;
    int c8 = t & 15;
    int es = t >> 4;
    int wave = t >> 6;
    int lane = t & 63;

    int e0 = offsets[i], e1 = offsets[i + 1];
    const ushort8_t* T8 = (const ushort8_t*)T;

    float acc[8];
#pragma unroll
    for (int j = 0; j < 8; ++j) acc[j] = 0.f;

    int e = e0 + es;
    for (; e + 16 < e1; e += 32) {
        int s0 = csr[e];
        int s1 = csr[e + 16];
        float w0 = dis[s0];
        float w1 = dis[s1];
        ushort8_t v0 = T8[(size_t)s0 * 16 + c8];
        ushort8_t v1 = T8[(size_t)s1 * 16 + c8];
#pragma unroll
        for (int j = 0; j < 8; ++j)
            acc[j] += w0 * bf2f(v0[j]) + w1 * bf2f(v1[j]);
    }
    if (e < e1) {
        int s0 = csr[e];
        float w0 = dis[s0];
        ushort8_t v0 = T8[(size_t)s0 * 16 + c8];
#pragma unroll
        for (int j = 0; j < 8; ++j) acc[j] += w0 * bf2f(v0[j]);
    }

#pragma unroll
    for (int j = 0; j < 8; ++j) {
        acc[j] += __shfl_xor(acc[j], 16, 64);
        acc[j] += __shfl_xor(acc[j], 32, 64);
    }
    if (wave > 0 && lane < 16) {
#pragma unroll
        for (int j = 0; j < 8; ++j) red[wave - 1][lane][j] = acc[j];
    }
    __syncthreads();
    if (wave == 0 && lane < 16) {
#pragma unroll
        for (int j = 0; j < 8; ++j)
            acc[j] += red[0][lane][j] + red[1][lane][j] + red[2][lane][j];

        float di = dis[i];
        ushort8_t sv = T8[(size_t)i * 16 + c8];
#pragma unroll
        for (int j = 0; j < 8; ++j) acc[j] += di * bf2f(sv[j]);

#pragma unroll
        for (int j = 0; j < 8; ++j) acc[j] = di * acc[j] + bias[c8 * 8 + j];

        if (MODE == 1) {
#pragma unroll
            for (int j = 0; j < 8; ++j) acc[j] = fmaxf(acc[j], 0.f);
        } else {
            const float4* rv4 = (const float4*)resid;
            float4 r0 = rv4[(size_t)i * 32 + c8 * 2];
            float4 r1 = rv4[(size_t)i * 32 + c8 * 2 + 1];
            acc[0] += r0.x; acc[1] += r0.y; acc[2] += r0.z; acc[3] += r0.w;
            acc[4] += r1.x; acc[5] += r1.y; acc[6] += r1.z; acc[7] += r1.w;
        }
        float4* Y4 = (float4*)Y;
        Y4[(size_t)i * 32 + c8 * 2]     = make_float4(acc[0], acc[1], acc[2], acc[3]);
        Y4[(size_t)i * 32 + c8 * 2 + 1] = make_float4(acc[4], acc[5], acc[6], acc[7]);
    }
}

// ---------------- fused heads ----------------
__global__ __launch_bounds__(256) void k_heads(const float* __restrict__ h,
                                               const float* __restrict__ Wlin,
                                               const float* __restrict__ blin,
                                               const float* __restrict__ Wd2,
                                               const float* __restrict__ bd2,
                                               const float* __restrict__ Wd3,
                                               const float* __restrict__ bd3,
                                               float* __restrict__ out1,
                                               float* __restrict__ out2,
                                               float* __restrict__ out3, int n) {
    int wid = (blockIdx.x * blockDim.x + threadIdx.x) >> 6;
    int lane = threadIdx.x & 63;
    if (wid >= n) return;
    int r = wid;
    float h0 = h[(size_t)r * 128 + lane];
    float h1 = h[(size_t)r * 128 + 64 + lane];
    float p2 = h0 * Wd2[lane] + h1 * Wd2[64 + lane];
    float p3 = h0 * Wd3[lane] + h1 * Wd3[64 + lane];
#pragma unroll
    for (int d = 1; d < 64; d <<= 1) {
        p2 += __shfl_xor(p2, d, 64);
        p3 += __shfl_xor(p3, d, 64);
    }
    if (lane == 0) {
        out2[r] = p2 + bd2[0];
        out3[r] = p3 + bd3[0];
    }
    int c = lane & 15, kg = lane >> 4;
    float z = 0.f;
#pragma unroll 8
    for (int j = 0; j < 32; ++j) {
        int k = kg * 32 + j;
        z += h[(size_t)r * 128 + k] * Wlin[k * 16 + c];
    }
    z += __shfl_xor(z, 16, 64);
    z += __shfl_xor(z, 32, 64);
    z += blin[c];
    float m = z;
#pragma unroll
    for (int d = 1; d < 16; d <<= 1) m = fmaxf(m, __shfl_xor(m, d, 64));
    float ex = expf(z - m);
    float ssum = ex;
#pragma unroll
    for (int d = 1; d < 16; d <<= 1) ssum += __shfl_xor(ssum, d, 64);
    float lsm = z - m - logf(ssum);
    if (lane < 16) out1[(size_t)r * 16 + c] = lsm;
}

extern "C" void kernel_launch(void* const* d_in, const int* in_sizes, int n_in,
                              void* d_out, int out_size, void* d_ws, size_t ws_size,
                              hipStream_t stream) {
    const float* x     = (const float*)d_in[0];
    const int*   ei    = (const int*)d_in[1];
    const float* W1    = (const float*)d_in[2];
    const float* b1    = (const float*)d_in[3];
    const float* W2    = (const float*)d_in[4];
    const float* b2    = (const float*)d_in[5];
    const float* Wlin1 = (const float*)d_in[6];
    const float* blin1 = (const float*)d_in[7];
    const float* Wdeg2 = (const float*)d_in[8];
    const float* bdeg2 = (const float*)d_in[9];
    const float* Wdeg3 = (const float*)d_in[10];
    const float* bdeg3 = (const float*)d_in[11];
    const float* Wdown = (const float*)d_in[12];
    const float* bdown = (const float*)d_in[13];

    const int n = N_NODES, E = N_EDGES;
    const int* src = ei;
    const int* dst = ei + E;

    char* ws = (char*)d_ws;
    int*            hmat    = (int*)ws;                         // NB*HP
    int*            bmat    = hmat + NB * HP;                   // NB*HP
    int*            deg     = bmat + NB * HP;                   // 10016
    int*            offsets = deg + HP;                         // 10016
    float*          dis     = (float*)(offsets + HP);           // 10016
    int*            csr     = (int*)(dis + HP);                 // 640000
    unsigned short* bufT    = (unsigned short*)(csr + E);       // bf16 10000*128
    float*          bufB    = (float*)(bufT + (size_t)n * 128); // f32 10000*128
    float*          bufC    = bufB + (size_t)n * 128;           // f32 10000*128

    k_hist<<<NB, 256, 0, stream>>>(dst, hmat);
    k_colsum<<<(n + 255) / 256, 256, 0, stream>>>(hmat, deg, dis);
    k_scan<<<1, 1024, 0, stream>>>(deg, offsets, n);
    k_base<<<(n + 255) / 256, 256, 0, stream>>>(hmat, offsets, bmat);
    k_scatter<<<NB, 256, 0, stream>>>(src, dst, bmat, csr);

    // T1 = x @ W1  (bf16 out; bias folded into agg)
    k_gemm<1><<<(n + 31) / 32, 256, 0, stream>>>(x, W1, nullptr, bufT, n);
    // orig = x @ Wdown + bdown  (f32)
    k_gemm<0><<<(n + 31) / 32, 256, 0, stream>>>(x, Wdown, bdown, bufB, n);
    // h1 = relu(agg(T1) + b1)  (f32)
    k_agg<1><<<n, 256, 0, stream>>>(bufT, dis, offsets, csr, b1, nullptr, bufC, n);
    // T2 = h1 @ W2  (bf16 out)
    k_gemm<1><<<(n + 31) / 32, 256, 0, stream>>>(bufC, W2, nullptr, bufT, n);
    // h2 = agg(T2) + b2 + orig
    k_agg<2><<<n, 256, 0, stream>>>(bufT, dis, offsets, csr, b2, bufB, bufC, n);

    float* out1 = (float*)d_out;
    float* out2 = out1 + (size_t)n * 16;
    float* out3 = out2 + n;
    k_heads<<<(n + 3) / 4, 256, 0, stream>>>(bufC, Wlin1, blin1, Wdeg2, bdeg2,
                                             Wdeg3, bdeg3, out1, out2, out3, n);
}